// Round 10
// baseline (200.952 us; speedup 1.0000x reference)
//
#include <hip/hip_runtime.h>
#include <hip/hip_bf16.h>

// Problem constants (from reference)
#define E_TOTAL 300000
#define N_NODES 50000
#define NDIM    128      // node feature dim (floats per node)
#define KDIM    256      // 2*NDIM = GEMM K
#define HDIM    512      // 2*HIDDEN = GEMM N (both MLP branches fused)
#define BN_EPS  1e-5f
#define NTILES  ((E_TOTAL + 63) / 64)   // 4688 tiles of 64 edges
#define NBLK    256                      // persistent blocks (1/CU by LDS, but NOT relied upon)
#define LT_MAX  19                       // max tiles per block

typedef __attribute__((ext_vector_type(8))) short bf16x8;
typedef __attribute__((ext_vector_type(4))) float f32x4;

__device__ __forceinline__ unsigned short f2bf(float f) {
  unsigned u = __float_as_uint(f);
  u += 0x7fffu + ((u >> 16) & 1u);   // round-to-nearest-even
  return (unsigned short)(u >> 16);
}
__device__ __forceinline__ unsigned pk2(float a, float b) {
  return (unsigned)f2bf(a) | ((unsigned)f2bf(b) << 16);
}

// DPP rotate-add stage over all 16 partials (VALU pipe, zero LDS traffic).
#define DPP_STAGE(C)                                                          \
  {                                                                           \
    _Pragma("unroll")                                                         \
    for (int i = 0; i < 16; i++) {                                            \
      int t = __builtin_amdgcn_update_dpp(0, __float_as_int(vs[i]),           \
                                          (C), 0xF, 0xF, true);               \
      vs[i] += __int_as_float(t);                                             \
    }                                                                         \
  }

// ---- single kernel, NO workspace, NO inter-block dependencies ----
// Per-block prologue: preload edge indices (LDS), build this wave's B fragments
// (BN-folded, roll-fused W1) + bias/w2 directly from inputs (L2-resident).
// Main loop identical to R8: 4-slot LDS ring of A tiles, one __syncthreads per
// pair of tiles, inline fp32 gather -> bf16 convert -> ds_write_b128 staging,
// 16x16x32 MFMA, DPP epilogue reduction.
__global__ __launch_bounds__(512, 2) void edge_mlp_kernel(
    const float* __restrict__ nf, const int* __restrict__ eidx,
    const float* __restrict__ W1, const float* __restrict__ b1,
    const float* __restrict__ gamma, const float* __restrict__ beta,
    const float* __restrict__ mean, const float* __restrict__ var,
    const float* __restrict__ W2, const float* __restrict__ b2,
    float* __restrict__ out) {
  __shared__ unsigned short Ab[4][32 * 512];   // 128 KB
  __shared__ int idxl[LT_MAX * 128];           // 9.5 KB
  __shared__ float partial[4][8][64];          // 8 KB, ring by tile&3

  const int tid  = threadIdx.x;
  const int w    = tid >> 6;
  const int lane = tid & 63;
  const int l16  = lane & 15;
  const int quad = lane >> 4;
  const int b    = blockIdx.x;
  const int ntl  = (NTILES - b + NBLK - 1) / NBLK;   // 18 or 19

  // ---- prologue A: preload ALL this block's edge indices into LDS ----
  for (int g = tid; g < ntl * 128; g += 512) {
    int lt2 = g >> 7, r = g & 127;
    int half = r >> 6;
    int e = (b + lt2 * NBLK) * 64 + (r & 63);
    if (e >= E_TOTAL) e = E_TOTAL - 1;
    idxl[g] = eidx[half * E_TOTAL + e];
  }

  // ---- prologue B: build B fragments + bias/w2 in-registers (wave-private) ----
  // bq[n][kt]: lane holds B[k = kt*32 + quad*8 + j][col = w*64 + n*16 + l16],
  // BN scale folded; col>=256 is the roll branch: W1[(k+16)&255].
  bf16x8 bq[4][8];
  float cj[4], w2j[4];
  #pragma unroll
  for (int n = 0; n < 4; n++) {
    int col = w * 64 + n * 16 + l16;
    int jj  = col & 255;
    float s = gamma[jj] * rsqrtf(var[jj] + BN_EPS);
    int shift = (col >= 256) ? 16 : 0;
    cj[n]  = b1[jj] * s + beta[jj] - mean[jj] * s;
    w2j[n] = 0.5f * W2[jj];            // fold the 0.5 average
    #pragma unroll
    for (int kt = 0; kt < 8; kt++) {
      unsigned short o[8];
      #pragma unroll
      for (int j = 0; j < 8; j++) {
        int k  = kt * 32 + quad * 8 + j;
        int ks = (k + shift) & 255;
        o[j] = f2bf(W1[ks * 256 + jj] * s);
      }
      bq[n][kt] = *(const bf16x8*)o;
    }
  }
  const float b2v = b2[0];

  __syncthreads();   // idxl ready

  // staging role (wave-constant): wave w stages frags f = sfrag0+i, i=0..3
  // covering edges smt*16..+16, k-half shalf (k = shalf*128 + i*32 + quad*8 + j)
  const int smt    = w & 3;
  const int shalf  = w >> 2;
  const int sfrag0 = smt * 8 + shalf * 4;

  auto stage = [&](int lt2, int slot) {
    int node = idxl[lt2 * 128 + shalf * 64 + smt * 16 + l16];
    const float* gbase = nf + (size_t)node * NDIM + quad * 8;
    #pragma unroll
    for (int i = 0; i < 4; i++) {
      float4 v0 = *(const float4*)(gbase + i * 32);
      float4 v1 = *(const float4*)(gbase + i * 32 + 4);
      uint4 pk;
      pk.x = pk2(v0.x, v0.y); pk.y = pk2(v0.z, v0.w);
      pk.z = pk2(v1.x, v1.y); pk.w = pk2(v1.z, v1.w);
      // same lane-stride-16B pattern as the ds_read side: conflict-free
      *(uint4*)(&Ab[slot][(sfrag0 + i) * 512 + lane * 8]) = pk;
    }
  };

  auto combine = [&](int lt2, int le) {
    int e = (b + lt2 * NBLK) * 64 + le;
    if (e < E_TOTAL) {
      float s = 0.f;
      #pragma unroll
      for (int ww = 0; ww < 8; ww++) s += partial[lt2 & 3][ww][le];
      out[e] = 1.0f / (1.0f + __expf(-(s + b2v)));
    }
  };

  auto compute_tile = [&](int lt2) {
    f32x4 acc[4][4] = {};
    const unsigned short* Ap = &Ab[lt2 & 3][lane * 8];
    #pragma unroll
    for (int kt = 0; kt < 8; kt++) {
      bf16x8 af[4];
      #pragma unroll
      for (int mt = 0; mt < 4; mt++)
        af[mt] = *(const bf16x8*)(Ap + (mt * 8 + kt) * 512);
      #pragma unroll
      for (int n = 0; n < 4; n++)
        #pragma unroll
        for (int mt = 0; mt < 4; mt++)
          acc[mt][n] = __builtin_amdgcn_mfma_f32_16x16x32_bf16(af[mt], bq[n][kt], acc[mt][n], 0, 0, 0);
    }

    // epilogue: relu(h+c)*w2 summed over my 4 col-tiles -> 16 independent values
    float vs[16];
    #pragma unroll
    for (int mt = 0; mt < 4; mt++)
      #pragma unroll
      for (int r = 0; r < 4; r++) {
        float v = 0.f;
        #pragma unroll
        for (int n = 0; n < 4; n++) {
          float h = acc[mt][n][r] + cj[n];
          v += fmaxf(h, 0.f) * w2j[n];
        }
        vs[mt * 4 + r] = v;
      }
    // 16-lane rotate-butterfly on the VALU pipe (DPP row_ror), 16-wide ILP/stage
    DPP_STAGE(0x128)   // ror 8
    DPP_STAGE(0x124)   // ror 4
    DPP_STAGE(0x122)   // ror 2
    DPP_STAGE(0x121)   // ror 1
    if (l16 == 0) {
      #pragma unroll
      for (int mt = 0; mt < 4; mt++)
        #pragma unroll
        for (int r = 0; r < 4; r++)
          partial[lt2 & 3][w][mt * 16 + quad * 4 + r] = vs[mt * 4 + r];
    }
  };

  // ---- prologue: stage tiles 0,1 ----
  stage(0, 0);
  if (1 < ntl) stage(1, 1);

  // ---- main loop: one barrier per PAIR of tiles ----
  for (int lt = 0; lt < ntl; lt += 2) {
    __syncthreads();   // staging of pair (lt,lt+1) complete; partial ring synced

    int s2 = lt + 2, s3 = lt + 3;
    if (s2 < ntl) stage(s2, s2 & 3);
    if (s3 < ntl) stage(s3, s3 & 3);

    if (lt >= 2) {
      if (tid < 64)       combine(lt - 2, tid);
      else if (tid < 128) combine(lt - 1, tid - 64);
    }

    compute_tile(lt);
    if (lt + 1 < ntl) compute_tile(lt + 1);
  }

  // ---- tail: combine the last pair ----
  __syncthreads();
  if ((ntl & 1) == 0) {
    if (tid < 64)       combine(ntl - 2, tid);
    else if (tid < 128) combine(ntl - 1, tid - 64);
  } else {
    if (tid < 64)       combine(ntl - 1, tid);
  }
}

extern "C" void kernel_launch(void* const* d_in, const int* in_sizes, int n_in,
                              void* d_out, int out_size, void* d_ws, size_t ws_size,
                              hipStream_t stream) {
  const float* node_feat = (const float*)d_in[0];
  const int*   eidx      = (const int*)d_in[1];
  const float* W1        = (const float*)d_in[2];
  const float* b1        = (const float*)d_in[3];
  const float* gamma     = (const float*)d_in[4];
  const float* beta      = (const float*)d_in[5];
  const float* mean      = (const float*)d_in[6];
  const float* var       = (const float*)d_in[7];
  const float* W2        = (const float*)d_in[8];
  const float* b2        = (const float*)d_in[9];
  float* out = (float*)d_out;

  // Single launch; no workspace, no inter-block dependencies, no grid barrier.
  edge_mlp_kernel<<<NBLK, 512, 0, stream>>>(node_feat, eidx, W1, b1, gamma, beta,
                                            mean, var, W2, b2, out);
}